// Round 1
// baseline (77.472 us; speedup 1.0000x reference)
//
#include <hip/hip_runtime.h>
#include <math.h>

#define TILE 8
#define HALO 2
#define LDIM (TILE + 2 * HALO)     // 12
#define LSZ  (LDIM * LDIM * LDIM)  // 1728
#define NVOX (TILE * TILE * TILE)  // 512

// 1 / radians(20)^2
#define INV_STH2 8.2070214911050910f

__global__ __launch_bounds__(256) void repulsion_kernel(
    const float* __restrict__ n_pred,   // (2,3,64,64,64)
    const float* __restrict__ src,      // (2,1,64,64,64)
    double* __restrict__ acc)           // acc[0]=total (double), acc[1]=count (ull)
{
    __shared__ float4 sn[LSZ];

    const int tx = blockIdx.x * TILE;
    const int ty = blockIdx.y * TILE;
    const int zb = blockIdx.z;          // 0..15 = batch*8 + ztile
    const int b  = zb >> 3;
    const int tz = (zb & 7) * TILE;

    const size_t cstride = 64 * 64 * 64;  // 262144
    const float* npb = n_pred + (size_t)b * 3 * cstride;
    const float* spb = src + (size_t)b * cstride;

    // Stage normalized normals + mask into LDS (halo of 2, zero outside volume).
    for (int i = threadIdx.x; i < LSZ; i += 256) {
        int lx = i % LDIM;
        int t  = i / LDIM;
        int ly = t % LDIM;
        int lz = t / LDIM;
        int gx = tx + lx - HALO;
        int gy = ty + ly - HALO;
        int gz = tz + lz - HALO;
        float4 v = make_float4(0.f, 0.f, 0.f, 0.f);
        if ((unsigned)gx < 64u && (unsigned)gy < 64u && (unsigned)gz < 64u) {
            size_t off = ((size_t)gz * 64 + gy) * 64 + gx;
            float x = npb[off];
            float y = npb[cstride + off];
            float z = npb[2 * cstride + off];
            float nrm = sqrtf(x * x + y * y + z * z);
            float inv = 1.0f / fmaxf(nrm, 1e-6f);
            // sigmoid(s) > 0.5  <=>  s > 0
            float m = (spb[off] > 0.0f) ? 1.0f : 0.0f;
            v = make_float4(x * inv, y * inv, z * inv, m);
        }
        sn[i] = v;
    }
    __syncthreads();

    double tot = 0.0;
    unsigned int cnt = 0;

    for (int v = threadIdx.x; v < NVOX; v += 256) {
        int lx = (v & 7) + HALO;
        int ly = ((v >> 3) & 7) + HALO;
        int lz = (v >> 6) + HALO;
        int ci = (lz * LDIM + ly) * LDIM + lx;
        float4 c = sn[ci];
        if (c.w != 0.0f) {
#pragma unroll
            for (int dz = -2; dz <= 2; ++dz) {
#pragma unroll
                for (int dy = -2; dy <= 2; ++dy) {
#pragma unroll
                    for (int dx = -2; dx <= 2; ++dx) {
                        if (dz == 0 && dy == 0 && dx == 0) continue;
                        // w_dist = exp(-d2 / (TAU/1.5)^2) = exp(-0.5625*d2); constant-folds.
                        const float wd =
                            expf(-0.5625f * (float)(dz * dz + dy * dy + dx * dx));
                        int ni = ci + (dz * LDIM + dy) * LDIM + dx;
                        float4 nb = sn[ni];
                        float dot = c.x * nb.x + c.y * nb.y + c.z * nb.z;
                        dot = fminf(1.0f, fmaxf(-1.0f, dot));
                        float th = acosf(dot);
                        float wt = __expf(-th * th * INV_STH2);
                        // nb.w is 0/1; pairs with masked-out neighbor contribute 0.
                        tot += (double)(wd * wt * nb.w);
                        cnt += (nb.w != 0.0f) ? 1u : 0u;
                    }
                }
            }
        }
    }

    // Wave (64-lane) reduction.
#pragma unroll
    for (int s = 32; s > 0; s >>= 1) {
        tot += __shfl_down(tot, s, 64);
        cnt += __shfl_down(cnt, s, 64);
    }

    __shared__ double sd[4];
    __shared__ unsigned int sc[4];
    int wid = threadIdx.x >> 6;
    int lane = threadIdx.x & 63;
    if (lane == 0) { sd[wid] = tot; sc[wid] = cnt; }
    __syncthreads();
    if (threadIdx.x == 0) {
        double T = sd[0] + sd[1] + sd[2] + sd[3];
        unsigned long long C =
            (unsigned long long)sc[0] + sc[1] + sc[2] + sc[3];
        atomicAdd(&acc[0], T);
        atomicAdd((unsigned long long*)&acc[1], C);
    }
}

__global__ void zero_acc_kernel(double* acc) {
    acc[0] = 0.0;
    ((unsigned long long*)acc)[1] = 0ull;
}

__global__ void finalize_kernel(const double* acc, float* out) {
    double t = acc[0];
    unsigned long long c = ((const unsigned long long*)acc)[1];
    out[0] = (c == 0ull) ? 0.0f : (float)(t / (double)c);
}

extern "C" void kernel_launch(void* const* d_in, const int* in_sizes, int n_in,
                              void* d_out, int out_size, void* d_ws, size_t ws_size,
                              hipStream_t stream) {
    const float* n_pred = (const float*)d_in[0];
    const float* src    = (const float*)d_in[1];
    double* acc = (double*)d_ws;

    zero_acc_kernel<<<1, 1, 0, stream>>>(acc);
    dim3 grid(8, 8, 16);
    repulsion_kernel<<<grid, 256, 0, stream>>>(n_pred, src, acc);
    finalize_kernel<<<1, 1, 0, stream>>>(acc, (float*)d_out);
}

// Round 2
// 45.691 us; speedup vs baseline: 1.6956x; 1.6956x over previous
//
#include <hip/hip_runtime.h>
#include <math.h>

#define TILE 8
#define HALO 2
#define LDIM 12          // TILE + 2*HALO
#define LSZ  1728        // 12^3
#define NVOX 512         // 8^3

// theta^2 = 2*u*h(u), u = 1-dot; arg = -theta^2/sigma_th^2 = KE*u*h(u)
// KE = -2 / radians(20)^2 = -16.4140429822
#define KE (-16.4140429822f)

__global__ __launch_bounds__(256) void repulsion_kernel(
    const float* __restrict__ n_pred,   // (2,3,64,64,64)
    const float* __restrict__ src,      // (2,1,64,64,64)
    double* __restrict__ acc)           // acc[0]=total, acc[1]=count
{
    __shared__ float4 sn[LSZ];
    __shared__ int s_list[NVOX];
    __shared__ int s_nact;
    __shared__ float rd[4], rc[4];

    if (threadIdx.x == 0) s_nact = 0;

    const int tx = blockIdx.x * TILE;
    const int ty = blockIdx.y * TILE;
    const int zb = blockIdx.z;          // batch*8 + ztile
    const int b  = zb >> 3;
    const int tz = (zb & 7) * TILE;

    const size_t cs = 262144;           // 64^3
    const float* npb = n_pred + (size_t)b * 3 * cs;
    const float* spb = src + (size_t)b * cs;

    // Stage normalized normals + mask (halo 2, zero outside = reference zero-pad).
    for (int i = threadIdx.x; i < LSZ; i += 256) {
        int lx = i % LDIM;
        int t  = i / LDIM;
        int ly = t % LDIM;
        int lz = t / LDIM;
        int gx = tx + lx - HALO;
        int gy = ty + ly - HALO;
        int gz = tz + lz - HALO;
        float4 v = make_float4(0.f, 0.f, 0.f, 0.f);
        if ((unsigned)gx < 64u && (unsigned)gy < 64u && (unsigned)gz < 64u) {
            size_t off = ((size_t)gz * 64 + gy) * 64 + gx;
            float x = npb[off];
            float y = npb[cs + off];
            float z = npb[2 * cs + off];
            float inv = 1.0f / fmaxf(sqrtf(x * x + y * y + z * z), 1e-6f);
            float m = (spb[off] > 0.0f) ? 1.0f : 0.0f;  // sigmoid(s)>0.5 <=> s>0
            v = make_float4(x * inv, y * inv, z * inv, m);
        }
        sn[i] = v;
    }
    __syncthreads();

    // Compact active (central-mask) voxels into an LDS list.
    for (int v = threadIdx.x; v < NVOX; v += 256) {
        int lx = (v & 7) + HALO;
        int ly = ((v >> 3) & 7) + HALO;
        int lz = (v >> 6) + HALO;
        int ci = (lz * LDIM + ly) * LDIM + lx;
        if (sn[ci].w != 0.0f) {
            int idx = atomicAdd(&s_nact, 1);
            s_list[idx] = ci;
        }
    }
    __syncthreads();

    const int nact = s_nact;
    float tot = 0.0f;
    float cf  = 0.0f;

    for (int j = threadIdx.x; j < nact; j += 256) {
        int ci = s_list[j];
        float4 c = sn[ci];
#pragma unroll
        for (int dz = -2; dz <= 2; ++dz) {
#pragma unroll
            for (int dy = -2; dy <= 2; ++dy) {
#pragma unroll
                for (int dx = -2; dx <= 2; ++dx) {
                    if (dz == 0 && dy == 0 && dx == 0) continue;
                    // ln(w_dist) = -0.5625*d^2 folded into the exp argument.
                    const float coff =
                        -0.5625f * (float)(dz * dz + dy * dy + dx * dx);
                    float4 nb = sn[ci + (dz * LDIM + dy) * LDIM + dx];
                    float dot = fmaf(c.x, nb.x, fmaf(c.y, nb.y, c.z * nb.z));
                    float u = 1.0f - dot;  // no clamp needed: rounding-safe
                    // P(u) = sum a_n (u/2)^n, a_n = asin-series coeffs; deg 6
                    float p = fmaf(u, 2.7113800e-4f, 6.9913100e-4f);
                    p = fmaf(u, p, 1.8990885e-3f);
                    p = fmaf(u, p, 5.5803571e-3f);
                    p = fmaf(u, p, 1.8750000e-2f);
                    p = fmaf(u, p, 8.3333333e-2f);
                    p = fmaf(u, p, 1.0f);
                    float h  = p * p;          // theta^2 = 2*u*h
                    float uh = u * h;
                    float w  = __expf(fmaf(KE, uh, coff));  // = w_dist * w_theta
                    tot = fmaf(w, nb.w, tot);  // neighbor mask gates contribution
                    cf += nb.w;                // exact: 0/1 floats, <=248 per lane
                }
            }
        }
    }

    // 64-lane wave reduction.
#pragma unroll
    for (int s = 32; s > 0; s >>= 1) {
        tot += __shfl_down(tot, s, 64);
        cf  += __shfl_down(cf, s, 64);
    }
    int wid = threadIdx.x >> 6;
    int lane = threadIdx.x & 63;
    if (lane == 0) { rd[wid] = tot; rc[wid] = cf; }
    __syncthreads();
    if (threadIdx.x == 0) {
        double T = (double)rd[0] + (double)rd[1] + (double)rd[2] + (double)rd[3];
        double C = (double)rc[0] + (double)rc[1] + (double)rc[2] + (double)rc[3];
        atomicAdd(&acc[0], T);
        atomicAdd(&acc[1], C);
    }
}

__global__ void zero_acc_kernel(double* acc) {
    acc[0] = 0.0;
    acc[1] = 0.0;
}

__global__ void finalize_kernel(const double* acc, float* out) {
    double t = acc[0];
    double c = acc[1];
    out[0] = (c == 0.0) ? 0.0f : (float)(t / c);
}

extern "C" void kernel_launch(void* const* d_in, const int* in_sizes, int n_in,
                              void* d_out, int out_size, void* d_ws, size_t ws_size,
                              hipStream_t stream) {
    const float* n_pred = (const float*)d_in[0];
    const float* src    = (const float*)d_in[1];
    double* acc = (double*)d_ws;

    zero_acc_kernel<<<1, 1, 0, stream>>>(acc);
    dim3 grid(8, 8, 16);
    repulsion_kernel<<<grid, 256, 0, stream>>>(n_pred, src, acc);
    finalize_kernel<<<1, 1, 0, stream>>>(acc, (float*)d_out);
}

// Round 3
// 36.005 us; speedup vs baseline: 2.1517x; 1.2690x over previous
//
#include <hip/hip_runtime.h>
#include <math.h>

#define PD 68                  // 64 + 2*2 halo
#define PVOL (PD * PD * PD)    // 314432
#define NBLK2 2048

// arg = -theta^2/sigma_th^2 = KE * u * h(u), u = 1 - dot
// KE = -2 / radians(20)^2
#define KE (-16.4140429822f)

// ---------------- two-pass path ----------------

__global__ __launch_bounds__(256) void normalize_kernel(
    const float* __restrict__ n_pred,   // (2,3,64,64,64)
    const float* __restrict__ src,      // (2,1,64,64,64)
    float4* __restrict__ q)             // (2,68,68,68) padded, halo pre-zeroed
{
    int x = threadIdx.x & 63;
    int y = blockIdx.x * 4 + (threadIdx.x >> 6);
    int z = blockIdx.y;
    int b = blockIdx.z;
    const size_t cs = 262144;  // 64^3
    size_t vox = ((size_t)z * 64 + y) * 64 + x;
    size_t off = (size_t)b * 3 * cs + vox;
    float xx = n_pred[off];
    float yy = n_pred[off + cs];
    float zz = n_pred[off + 2 * cs];
    float inv = 1.0f / fmaxf(sqrtf(xx * xx + yy * yy + zz * zz), 1e-6f);
    float m = (src[(size_t)b * cs + vox] > 0.0f) ? 1.0f : 0.0f;  // sigmoid>0.5
    q[(size_t)b * PVOL + ((size_t)(z + 2) * PD + (y + 2)) * PD + (x + 2)] =
        make_float4(xx * inv, yy * inv, zz * inv, m);
}

__global__ __launch_bounds__(256) void stencil_kernel(
    const float4* __restrict__ q, float2* __restrict__ partials)
{
    int x = threadIdx.x & 63;
    int y = blockIdx.x * 4 + (threadIdx.x >> 6);
    int z = blockIdx.y;
    int b = blockIdx.z;
    const float4* cp =
        q + (size_t)b * PVOL + ((size_t)(z + 2) * PD + (y + 2)) * PD + (x + 2);
    float4 c = cp[0];
    float tot = 0.0f, cf = 0.0f;
    if (c.w != 0.0f) {
        // Positive-half stencil (62 taps): by symmetry total/count are exactly
        // half the full-stencil sums, so the ratio is unchanged.
#pragma unroll
        for (int dz = 0; dz <= 2; ++dz) {
#pragma unroll
            for (int dy = -2; dy <= 2; ++dy) {
#pragma unroll
                for (int dx = -2; dx <= 2; ++dx) {
                    if (dz == 0 && dy < 0) continue;
                    if (dz == 0 && dy == 0 && dx <= 0) continue;
                    const float coff =
                        -0.5625f * (float)(dz * dz + dy * dy + dx * dx);
                    float4 nb = cp[(dz * PD + dy) * PD + dx];
                    float dot = fmaf(c.x, nb.x, fmaf(c.y, nb.y, c.z * nb.z));
                    float u = 1.0f - dot;
                    // theta^2 = 2*u*P(u)^2, asin-series, degree 4 (bias < 3e-6 rel)
                    float p = fmaf(u, 1.8990885e-3f, 5.5803571e-3f);
                    p = fmaf(u, p, 1.8750000e-2f);
                    p = fmaf(u, p, 8.3333333e-2f);
                    p = fmaf(u, p, 1.0f);
                    float uh = u * p * p;
                    float w = __expf(fmaf(KE, uh, coff));  // w_dist * w_theta
                    tot = fmaf(w, nb.w, tot);
                    cf += nb.w;
                }
            }
        }
    }
#pragma unroll
    for (int s = 32; s > 0; s >>= 1) {
        tot += __shfl_down(tot, s, 64);
        cf  += __shfl_down(cf, s, 64);
    }
    __shared__ float sd[4], sc[4];
    int wid = threadIdx.x >> 6, lane = threadIdx.x & 63;
    if (lane == 0) { sd[wid] = tot; sc[wid] = cf; }
    __syncthreads();
    if (threadIdx.x == 0) {
        int bid = ((int)blockIdx.z * gridDim.y + blockIdx.y) * gridDim.x
                  + blockIdx.x;
        partials[bid] = make_float2(sd[0] + sd[1] + sd[2] + sd[3],
                                    sc[0] + sc[1] + sc[2] + sc[3]);
    }
}

__global__ __launch_bounds__(256) void reduce_kernel(
    const float2* __restrict__ partials, float* __restrict__ out)
{
    double t = 0.0, c = 0.0;
    for (int i = threadIdx.x; i < NBLK2; i += 256) {
        float2 p = partials[i];
        t += (double)p.x;
        c += (double)p.y;
    }
#pragma unroll
    for (int s = 32; s > 0; s >>= 1) {
        t += __shfl_down(t, s, 64);
        c += __shfl_down(c, s, 64);
    }
    __shared__ double sd[4], sc[4];
    int wid = threadIdx.x >> 6, lane = threadIdx.x & 63;
    if (lane == 0) { sd[wid] = t; sc[wid] = c; }
    __syncthreads();
    if (threadIdx.x == 0) {
        double T = sd[0] + sd[1] + sd[2] + sd[3];
        double C = sc[0] + sc[1] + sc[2] + sc[3];
        out[0] = (C == 0.0) ? 0.0f : (float)(T / C);
    }
}

// ---------------- fallback (round-2 fused) if ws too small ----------------

#define TILE 8
#define HALO 2
#define LDIM 12
#define LSZ  1728
#define NVOX 512

__global__ __launch_bounds__(256) void repulsion_fused_kernel(
    const float* __restrict__ n_pred, const float* __restrict__ src,
    double* __restrict__ acc)
{
    __shared__ float4 sn[LSZ];
    __shared__ int s_list[NVOX];
    __shared__ int s_nact;
    __shared__ float rd[4], rc[4];
    if (threadIdx.x == 0) s_nact = 0;
    const int tx = blockIdx.x * TILE, ty = blockIdx.y * TILE;
    const int b = blockIdx.z >> 3, tz = (blockIdx.z & 7) * TILE;
    const size_t cs = 262144;
    const float* npb = n_pred + (size_t)b * 3 * cs;
    const float* spb = src + (size_t)b * cs;
    for (int i = threadIdx.x; i < LSZ; i += 256) {
        int lx = i % LDIM, t = i / LDIM, ly = t % LDIM, lz = t / LDIM;
        int gx = tx + lx - HALO, gy = ty + ly - HALO, gz = tz + lz - HALO;
        float4 v = make_float4(0.f, 0.f, 0.f, 0.f);
        if ((unsigned)gx < 64u && (unsigned)gy < 64u && (unsigned)gz < 64u) {
            size_t off = ((size_t)gz * 64 + gy) * 64 + gx;
            float x = npb[off], y = npb[cs + off], z = npb[2 * cs + off];
            float inv = 1.0f / fmaxf(sqrtf(x * x + y * y + z * z), 1e-6f);
            float m = (spb[off] > 0.0f) ? 1.0f : 0.0f;
            v = make_float4(x * inv, y * inv, z * inv, m);
        }
        sn[i] = v;
    }
    __syncthreads();
    for (int v = threadIdx.x; v < NVOX; v += 256) {
        int lx = (v & 7) + HALO, ly = ((v >> 3) & 7) + HALO, lz = (v >> 6) + HALO;
        int ci = (lz * LDIM + ly) * LDIM + lx;
        if (sn[ci].w != 0.0f) s_list[atomicAdd(&s_nact, 1)] = ci;
    }
    __syncthreads();
    const int nact = s_nact;
    float tot = 0.0f, cf = 0.0f;
    for (int j = threadIdx.x; j < nact; j += 256) {
        int ci = s_list[j];
        float4 c = sn[ci];
#pragma unroll
        for (int dz = -2; dz <= 2; ++dz)
#pragma unroll
            for (int dy = -2; dy <= 2; ++dy)
#pragma unroll
                for (int dx = -2; dx <= 2; ++dx) {
                    if (dz == 0 && dy == 0 && dx == 0) continue;
                    const float coff =
                        -0.5625f * (float)(dz * dz + dy * dy + dx * dx);
                    float4 nb = sn[ci + (dz * LDIM + dy) * LDIM + dx];
                    float dot = fmaf(c.x, nb.x, fmaf(c.y, nb.y, c.z * nb.z));
                    float u = 1.0f - dot;
                    float p = fmaf(u, 1.8990885e-3f, 5.5803571e-3f);
                    p = fmaf(u, p, 1.8750000e-2f);
                    p = fmaf(u, p, 8.3333333e-2f);
                    p = fmaf(u, p, 1.0f);
                    float uh = u * p * p;
                    float w = __expf(fmaf(KE, uh, coff));
                    tot = fmaf(w, nb.w, tot);
                    cf += nb.w;
                }
    }
#pragma unroll
    for (int s = 32; s > 0; s >>= 1) {
        tot += __shfl_down(tot, s, 64);
        cf  += __shfl_down(cf, s, 64);
    }
    int wid = threadIdx.x >> 6, lane = threadIdx.x & 63;
    if (lane == 0) { rd[wid] = tot; rc[wid] = cf; }
    __syncthreads();
    if (threadIdx.x == 0) {
        atomicAdd(&acc[0], (double)rd[0] + rd[1] + rd[2] + rd[3]);
        atomicAdd(&acc[1], (double)rc[0] + rc[1] + rc[2] + rc[3]);
    }
}

__global__ void zero_acc_kernel(double* acc) { acc[0] = 0.0; acc[1] = 0.0; }

__global__ void finalize_kernel(const double* acc, float* out) {
    out[0] = (acc[1] == 0.0) ? 0.0f : (float)(acc[0] / acc[1]);
}

// ---------------- launch ----------------

extern "C" void kernel_launch(void* const* d_in, const int* in_sizes, int n_in,
                              void* d_out, int out_size, void* d_ws, size_t ws_size,
                              hipStream_t stream) {
    const float* n_pred = (const float*)d_in[0];
    const float* src    = (const float*)d_in[1];

    const size_t vol_bytes = (size_t)2 * PVOL * sizeof(float4);  // 10,061,824
    const size_t need = vol_bytes + (size_t)NBLK2 * sizeof(float2);

    if (ws_size >= need) {
        hipMemsetAsync(d_ws, 0, vol_bytes, stream);  // zero halo (and interior)
        float4* q = (float4*)d_ws;
        float2* partials = (float2*)((char*)d_ws + vol_bytes);
        dim3 grid(16, 64, 2);
        normalize_kernel<<<grid, 256, 0, stream>>>(n_pred, src, q);
        stencil_kernel<<<grid, 256, 0, stream>>>(q, partials);
        reduce_kernel<<<1, 256, 0, stream>>>(partials, (float*)d_out);
    } else {
        double* acc = (double*)d_ws;
        zero_acc_kernel<<<1, 1, 0, stream>>>(acc);
        dim3 grid(8, 8, 16);
        repulsion_fused_kernel<<<grid, 256, 0, stream>>>(n_pred, src, acc);
        finalize_kernel<<<1, 1, 0, stream>>>(acc, (float*)d_out);
    }
}

// Round 4
// 32.585 us; speedup vs baseline: 2.3775x; 1.1050x over previous
//
#include <hip/hip_runtime.h>
#include <math.h>

#define PD 68                  // 64 + 2*2 halo
#define PD2 (PD * PD)          // 4624
#define PVOL (PD * PD * PD)    // 314432
#define NBLK2 2048

// arg = -theta^2/sigma_th^2 = KE * u * h(u), u = 1 - dot
// KE = -2 / radians(20)^2
#define KE (-16.4140429822f)

// ---------------- pass 1: normalize + zero-pad (no memset needed) ------------

__global__ __launch_bounds__(256) void pad_normalize_kernel(
    const float* __restrict__ n_pred,   // (2,3,64,64,64)
    const float* __restrict__ src,      // (2,1,64,64,64)
    float4* __restrict__ q)             // (2,68,68,68) padded
{
    int idx = blockIdx.x * 256 + threadIdx.x;
    if (idx >= 2 * PVOL) return;
    int b = idx / PVOL;
    int r = idx - b * PVOL;
    int z = r / PD2;
    int r2 = r - z * PD2;
    int y = r2 / PD;
    int x = r2 - y * PD;
    int gx = x - 2, gy = y - 2, gz = z - 2;
    float4 v = make_float4(0.f, 0.f, 0.f, 0.f);
    if ((unsigned)gx < 64u && (unsigned)gy < 64u && (unsigned)gz < 64u) {
        const size_t cs = 262144;  // 64^3
        size_t vox = ((size_t)gz * 64 + gy) * 64 + gx;
        size_t off = (size_t)b * 3 * cs + vox;
        float xx = n_pred[off];
        float yy = n_pred[off + cs];
        float zz = n_pred[off + 2 * cs];
        float inv = 1.0f / fmaxf(sqrtf(xx * xx + yy * yy + zz * zz), 1e-6f);
        float m = (src[(size_t)b * cs + vox] > 0.0f) ? 1.0f : 0.0f;  // sig>0.5
        v = make_float4(xx * inv, yy * inv, zz * inv, m);
    }
    q[idx] = v;
}

// ---------------- pass 2: half-stencil accumulate ----------------------------

__global__ __launch_bounds__(256) void stencil_kernel(
    const float4* __restrict__ q, float2* __restrict__ partials)
{
    int x = threadIdx.x & 63;
    int y = blockIdx.x * 4 + (threadIdx.x >> 6);
    int z = blockIdx.y;
    int b = blockIdx.z;
    const float4* cp =
        q + (size_t)b * PVOL + ((size_t)(z + 2) * PD + (y + 2)) * PD + (x + 2);
    float4 c = cp[0];
    float tot = 0.0f, cf = 0.0f;
    if (c.w != 0.0f) {
        // Positive-half stencil (62 taps): w(i,j) symmetric => total and count
        // are exactly half the full sums; ratio unchanged.
#pragma unroll
        for (int dz = 0; dz <= 2; ++dz) {
#pragma unroll
            for (int dy = -2; dy <= 2; ++dy) {
#pragma unroll
                for (int dx = -2; dx <= 2; ++dx) {
                    if (dz == 0 && dy < 0) continue;
                    if (dz == 0 && dy == 0 && dx <= 0) continue;
                    const float coff =
                        -0.5625f * (float)(dz * dz + dy * dy + dx * dx);
                    float4 nb = cp[(dz * PD + dy) * PD + dx];
                    float dot = fmaf(c.x, nb.x, fmaf(c.y, nb.y, c.z * nb.z));
                    float u = 1.0f - dot;
                    // theta^2 = 2*u*P(u)^2, asin series, deg 4 (bias < 3e-6 rel)
                    float p = fmaf(u, 1.8990885e-3f, 5.5803571e-3f);
                    p = fmaf(u, p, 1.8750000e-2f);
                    p = fmaf(u, p, 8.3333333e-2f);
                    p = fmaf(u, p, 1.0f);
                    float uh = u * p * p;
                    float w = __expf(fmaf(KE, uh, coff));  // w_dist * w_theta
                    tot = fmaf(w, nb.w, tot);
                    cf += nb.w;
                }
            }
        }
    }
#pragma unroll
    for (int s = 32; s > 0; s >>= 1) {
        tot += __shfl_down(tot, s, 64);
        cf  += __shfl_down(cf, s, 64);
    }
    __shared__ float sd[4], sc[4];
    int wid = threadIdx.x >> 6, lane = threadIdx.x & 63;
    if (lane == 0) { sd[wid] = tot; sc[wid] = cf; }
    __syncthreads();
    if (threadIdx.x == 0) {
        int bid = ((int)blockIdx.z * gridDim.y + blockIdx.y) * gridDim.x
                  + blockIdx.x;
        partials[bid] = make_float2(sd[0] + sd[1] + sd[2] + sd[3],
                                    sc[0] + sc[1] + sc[2] + sc[3]);
    }
}

__global__ __launch_bounds__(256) void reduce_kernel(
    const float2* __restrict__ partials, float* __restrict__ out)
{
    double t = 0.0, c = 0.0;
    for (int i = threadIdx.x; i < NBLK2; i += 256) {
        float2 p = partials[i];
        t += (double)p.x;
        c += (double)p.y;
    }
#pragma unroll
    for (int s = 32; s > 0; s >>= 1) {
        t += __shfl_down(t, s, 64);
        c += __shfl_down(c, s, 64);
    }
    __shared__ double sd[4], sc[4];
    int wid = threadIdx.x >> 6, lane = threadIdx.x & 63;
    if (lane == 0) { sd[wid] = t; sc[wid] = c; }
    __syncthreads();
    if (threadIdx.x == 0) {
        double T = sd[0] + sd[1] + sd[2] + sd[3];
        double C = sc[0] + sc[1] + sc[2] + sc[3];
        out[0] = (C == 0.0) ? 0.0f : (float)(T / C);
    }
}

// ---------------- fallback (fused, single kernel) if ws too small ------------

#define TILE 8
#define HALO 2
#define LDIM 12
#define LSZ  1728
#define NVOX 512

__global__ __launch_bounds__(256) void repulsion_fused_kernel(
    const float* __restrict__ n_pred, const float* __restrict__ src,
    double* __restrict__ acc)
{
    __shared__ float4 sn[LSZ];
    __shared__ float rd[4], rc[4];
    const int tx = blockIdx.x * TILE, ty = blockIdx.y * TILE;
    const int b = blockIdx.z >> 3, tz = (blockIdx.z & 7) * TILE;
    const size_t cs = 262144;
    const float* npb = n_pred + (size_t)b * 3 * cs;
    const float* spb = src + (size_t)b * cs;
    for (int i = threadIdx.x; i < LSZ; i += 256) {
        int lx = i % LDIM, t = i / LDIM, ly = t % LDIM, lz = t / LDIM;
        int gx = tx + lx - HALO, gy = ty + ly - HALO, gz = tz + lz - HALO;
        float4 v = make_float4(0.f, 0.f, 0.f, 0.f);
        if ((unsigned)gx < 64u && (unsigned)gy < 64u && (unsigned)gz < 64u) {
            size_t off = ((size_t)gz * 64 + gy) * 64 + gx;
            float x = npb[off], y = npb[cs + off], z = npb[2 * cs + off];
            float inv = 1.0f / fmaxf(sqrtf(x * x + y * y + z * z), 1e-6f);
            float m = (spb[off] > 0.0f) ? 1.0f : 0.0f;
            v = make_float4(x * inv, y * inv, z * inv, m);
        }
        sn[i] = v;
    }
    __syncthreads();
    float tot = 0.0f, cf = 0.0f;
    for (int v = threadIdx.x; v < NVOX; v += 256) {
        int lx = (v & 7) + HALO, ly = ((v >> 3) & 7) + HALO, lz = (v >> 6) + HALO;
        int ci = (lz * LDIM + ly) * LDIM + lx;
        float4 c = sn[ci];
        if (c.w == 0.0f) continue;
#pragma unroll
        for (int dz = -2; dz <= 2; ++dz)
#pragma unroll
            for (int dy = -2; dy <= 2; ++dy)
#pragma unroll
                for (int dx = -2; dx <= 2; ++dx) {
                    if (dz == 0 && dy == 0 && dx == 0) continue;
                    const float coff =
                        -0.5625f * (float)(dz * dz + dy * dy + dx * dx);
                    float4 nb = sn[ci + (dz * LDIM + dy) * LDIM + dx];
                    float dot = fmaf(c.x, nb.x, fmaf(c.y, nb.y, c.z * nb.z));
                    float u = 1.0f - dot;
                    float p = fmaf(u, 1.8990885e-3f, 5.5803571e-3f);
                    p = fmaf(u, p, 1.8750000e-2f);
                    p = fmaf(u, p, 8.3333333e-2f);
                    p = fmaf(u, p, 1.0f);
                    float uh = u * p * p;
                    float w = __expf(fmaf(KE, uh, coff));
                    tot = fmaf(w, nb.w, tot);
                    cf += nb.w;
                }
    }
#pragma unroll
    for (int s = 32; s > 0; s >>= 1) {
        tot += __shfl_down(tot, s, 64);
        cf  += __shfl_down(cf, s, 64);
    }
    int wid = threadIdx.x >> 6, lane = threadIdx.x & 63;
    if (lane == 0) { rd[wid] = tot; rc[wid] = cf; }
    __syncthreads();
    if (threadIdx.x == 0) {
        atomicAdd(&acc[0], (double)rd[0] + rd[1] + rd[2] + rd[3]);
        atomicAdd(&acc[1], (double)rc[0] + rc[1] + rc[2] + rc[3]);
    }
}

__global__ void zero_acc_kernel(double* acc) { acc[0] = 0.0; acc[1] = 0.0; }

__global__ void finalize_kernel(const double* acc, float* out) {
    out[0] = (acc[1] == 0.0) ? 0.0f : (float)(acc[0] / acc[1]);
}

// ---------------- launch -----------------------------------------------------

extern "C" void kernel_launch(void* const* d_in, const int* in_sizes, int n_in,
                              void* d_out, int out_size, void* d_ws, size_t ws_size,
                              hipStream_t stream) {
    const float* n_pred = (const float*)d_in[0];
    const float* src    = (const float*)d_in[1];

    const size_t vol_bytes = (size_t)2 * PVOL * sizeof(float4);  // 10,061,824
    const size_t need = vol_bytes + (size_t)NBLK2 * sizeof(float2);

    if (ws_size >= need) {
        float4* q = (float4*)d_ws;
        float2* partials = (float2*)((char*)d_ws + vol_bytes);
        int nblk = (2 * PVOL + 255) / 256;  // 2457
        pad_normalize_kernel<<<nblk, 256, 0, stream>>>(n_pred, src, q);
        dim3 grid(16, 64, 2);
        stencil_kernel<<<grid, 256, 0, stream>>>(q, partials);
        reduce_kernel<<<1, 256, 0, stream>>>(partials, (float*)d_out);
    } else {
        double* acc = (double*)d_ws;
        zero_acc_kernel<<<1, 1, 0, stream>>>(acc);
        dim3 grid(8, 8, 16);
        repulsion_fused_kernel<<<grid, 256, 0, stream>>>(n_pred, src, acc);
        finalize_kernel<<<1, 1, 0, stream>>>(acc, (float*)d_out);
    }
}